// Round 7
// baseline (2889.274 us; speedup 1.0000x reference)
//
#include <hip/hip_runtime.h>

// B=64, S=512, I=256, O=256 fp32 LSTM.
// out = [h_seq (64*512*256)] [hT (64*256)] [cT (64*256)]
//
// Phase A: xg = x @ Wx^T + bx + bh  (fp32 LDS-tiled GEMM, known-good)
// Phase B (MFMA scan, single-barrier): 64 blocks x 1 batch, 512 threads
//   (8 waves, 2/SIMD -> 256 unified regs/wave cap). Wave w owns rows
//   g*256 + w*32 + i*16 (j = g*2+i, 8 tiles). k<192: A-frags in regs
//   (8x6 v8h = 192). k in [192,256): fp16 in LDS (128 KB).
//   MFMA D/C layout: col=lane&15 (batch, only col 0 real), row=q*4+r.
//   => lane (q, l15==0) holds ALL FOUR gates for p = w*32+i*16+q*4+r in
//   D[g][r] -> gate math fully in-register, no ylds, ONE barrier/step.
//   xg transposed to gate lanes via xld double buffer (written in step t
//   for t+1, crosses the barrier). h -> hbuf double buffer (ds_write_b64).
//   h_seq stores deferred one step (drain under MFMA phase).

#define SS 512

typedef _Float16 v8h __attribute__((ext_vector_type(8)));
typedef _Float16 v4h __attribute__((ext_vector_type(4)));
typedef float vf4 __attribute__((ext_vector_type(4)));

__device__ __forceinline__ float sigm(float x) { return 1.f / (1.f + __expf(-x)); }
__device__ __forceinline__ float tanh_f(float x) {
  float e = __expf(-2.f * fabsf(x));
  float r = (1.f - e) / (1.f + e);
  return copysignf(r, x);
}

// ---------------------------------------------------------------- Phase A
__global__ __launch_bounds__(256) void xg_gemm(
    const float* __restrict__ X, const float* __restrict__ W,
    const float* __restrict__ bx, const float* __restrict__ bh,
    float* __restrict__ out)
{
  __shared__ float As[64][68];
  __shared__ float Bs[64][68];
  const int bm = blockIdx.x >> 4;
  const int bn = blockIdx.x & 15;
  const int tid = threadIdx.x;
  const int tn = tid & 15, tm = tid >> 4;
  const int row0 = bm * 64, col0 = bn * 64;
  float acc[4][4] = {};

  for (int k0 = 0; k0 < 256; k0 += 64) {
#pragma unroll
    for (int i = 0; i < 4; i++) {
      const int m = (tid >> 4) + i * 16;
      const int k = (tid & 15) * 4;
      float4 av = *(const float4*)&X[(size_t)(row0 + m) * 256 + k0 + k];
      *(float4*)&As[m][k] = av;
      float4 wv = *(const float4*)&W[(size_t)(col0 + m) * 256 + k0 + k];
      Bs[k + 0][m] = wv.x; Bs[k + 1][m] = wv.y;
      Bs[k + 2][m] = wv.z; Bs[k + 3][m] = wv.w;
    }
    __syncthreads();
#pragma unroll 8
    for (int kk = 0; kk < 64; kk++) {
      const float a0 = As[tm * 4 + 0][kk];
      const float a1 = As[tm * 4 + 1][kk];
      const float a2 = As[tm * 4 + 2][kk];
      const float a3 = As[tm * 4 + 3][kk];
      const float4 bv = *(const float4*)&Bs[kk][tn * 4];
      acc[0][0] = fmaf(a0, bv.x, acc[0][0]); acc[0][1] = fmaf(a0, bv.y, acc[0][1]);
      acc[0][2] = fmaf(a0, bv.z, acc[0][2]); acc[0][3] = fmaf(a0, bv.w, acc[0][3]);
      acc[1][0] = fmaf(a1, bv.x, acc[1][0]); acc[1][1] = fmaf(a1, bv.y, acc[1][1]);
      acc[1][2] = fmaf(a1, bv.z, acc[1][2]); acc[1][3] = fmaf(a1, bv.w, acc[1][3]);
      acc[2][0] = fmaf(a2, bv.x, acc[2][0]); acc[2][1] = fmaf(a2, bv.y, acc[2][1]);
      acc[2][2] = fmaf(a2, bv.z, acc[2][2]); acc[2][3] = fmaf(a2, bv.w, acc[2][3]);
      acc[3][0] = fmaf(a3, bv.x, acc[3][0]); acc[3][1] = fmaf(a3, bv.y, acc[3][1]);
      acc[3][2] = fmaf(a3, bv.z, acc[3][2]); acc[3][3] = fmaf(a3, bv.w, acc[3][3]);
    }
    __syncthreads();
  }

  float bias[4];
#pragma unroll
  for (int j = 0; j < 4; j++) {
    const int col = col0 + tn * 4 + j;
    bias[j] = bx[col] + bh[col];
  }
#pragma unroll
  for (int i = 0; i < 4; i++) {
    float4 o4;
    o4.x = acc[i][0] + bias[0]; o4.y = acc[i][1] + bias[1];
    o4.z = acc[i][2] + bias[2]; o4.w = acc[i][3] + bias[3];
    *(float4*)&out[(size_t)(row0 + tm * 4 + i) * 1024 + col0 + tn * 4] = o4;
  }
}

// ---------------------------------------------------------------- Phase B
__global__ __launch_bounds__(512) void lstm_scan7(
    const float* __restrict__ xg,   // [64][512][1024]
    const float* __restrict__ Wh,   // [1024][256]  row = g*256+p, col = k
    const float* __restrict__ h0,   // [64][256]
    const float* __restrict__ c0,   // [64][256]
    float* __restrict__ out)
{
  __shared__ __align__(16) _Float16 wtail[8][8][2][64][8];  // 128 KB
  __shared__ __align__(16) _Float16 hbuf[2][256];           // 1 KB
  __shared__ __align__(16) float xld[2][1024];              // 8 KB

  const int tid  = threadIdx.x;
  const int b    = blockIdx.x;
  const int w    = tid >> 6;
  const int lane = tid & 63;
  const int q    = lane >> 4;
  const int l15  = lane & 15;
  const bool act = (l15 == 0);
  const int pb   = w * 32 + q * 4;      // pass i adds i*16

  // ---- A-frags k<192 (192 regs); tail k in [192,256) -> LDS
  v8h A[8][6];
#pragma unroll
  for (int j = 0; j < 8; ++j) {
    const int g = j >> 1, i = j & 1;
    const float* rp = Wh + (size_t)(g * 256 + w * 32 + i * 16 + l15) * 256 + q * 8;
#pragma unroll
    for (int kf = 0; kf < 6; ++kf) {
      float4 lo = *(const float4*)(rp + kf * 32);
      float4 hi = *(const float4*)(rp + kf * 32 + 4);
      v8h a;
      a[0] = (_Float16)lo.x; a[1] = (_Float16)lo.y;
      a[2] = (_Float16)lo.z; a[3] = (_Float16)lo.w;
      a[4] = (_Float16)hi.x; a[5] = (_Float16)hi.y;
      a[6] = (_Float16)hi.z; a[7] = (_Float16)hi.w;
      A[j][kf] = a;
    }
#pragma unroll
    for (int kfi = 0; kfi < 2; ++kfi) {
      float4 lo = *(const float4*)(rp + 192 + kfi * 32);
      float4 hi = *(const float4*)(rp + 192 + kfi * 32 + 4);
      _Float16* dst = &wtail[w][j][kfi][lane][0];
      dst[0] = (_Float16)lo.x; dst[1] = (_Float16)lo.y;
      dst[2] = (_Float16)lo.z; dst[3] = (_Float16)lo.w;
      dst[4] = (_Float16)hi.x; dst[5] = (_Float16)hi.y;
      dst[6] = (_Float16)hi.z; dst[7] = (_Float16)hi.w;
    }
  }

  // ---- initial state
  if (tid < 256) hbuf[0][tid] = (_Float16)h0[(size_t)b * 256 + tid];
  const float* xb = xg + (size_t)b * SS * 1024;
  {  // xld[0] <- xg(t=0)
    float2 v = *(const float2*)&xb[2 * tid];
    *(float2*)&xld[0][2 * tid] = v;
  }
  float4 cs[2] = {{0, 0, 0, 0}, {0, 0, 0, 0}};
  float4 hp[2] = {{0, 0, 0, 0}, {0, 0, 0, 0}};
  if (act) {
#pragma unroll
    for (int i = 0; i < 2; ++i)
      cs[i] = *(const float4*)&c0[(size_t)b * 256 + pb + i * 16];
  }
  __syncthreads();

  float* hs = out + (size_t)b * SS * 256;

  for (int t = 0; t < SS; ++t) {
    const int cb = t & 1, nb = cb ^ 1;

    // prefetch xg(t+1) -> regs (ds_write near end of step)
    float2 xpre = {0.f, 0.f};
    if (t + 1 < SS) xpre = *(const float2*)&xb[(size_t)(t + 1) * 1024 + 2 * tid];

    // deferred h_seq store for t-1 (drains under MFMA phase)
    if (t > 0 && act) {
      *(float4*)&hs[(size_t)(t - 1) * 256 + pb] = hp[0];
      *(float4*)&hs[(size_t)(t - 1) * 256 + pb + 16] = hp[1];
    }

    // ---- two passes over i; D[4] reused; gates fully in-register
#pragma unroll
    for (int pass = 0; pass < 2; ++pass) {
      vf4 D[4];
#pragma unroll
      for (int g = 0; g < 4; ++g) { vf4 z = {0.f, 0.f, 0.f, 0.f}; D[g] = z; }
#pragma unroll
      for (int kf = 0; kf < 6; ++kf) {
        v8h Bf = *(const v8h*)&hbuf[cb][kf * 32 + q * 8];
#pragma unroll
        for (int g = 0; g < 4; ++g)
          D[g] = __builtin_amdgcn_mfma_f32_16x16x32_f16(
              A[g * 2 + pass][kf], Bf, D[g], 0, 0, 0);
      }
#pragma unroll
      for (int kfi = 0; kfi < 2; ++kfi) {
        v8h Bf = *(const v8h*)&hbuf[cb][(6 + kfi) * 32 + q * 8];
#pragma unroll
        for (int g = 0; g < 4; ++g) {
          v8h wt = *(const v8h*)&wtail[w][g * 2 + pass][kfi][lane][0];
          D[g] = __builtin_amdgcn_mfma_f32_16x16x32_f16(wt, Bf, D[g], 0, 0, 0);
        }
      }

      if (act) {
        const int P = pb + pass * 16;
        float4 xf = *(const float4*)&xld[cb][0 * 256 + P];
        float4 xi = *(const float4*)&xld[cb][1 * 256 + P];
        float4 xgv = *(const float4*)&xld[cb][2 * 256 + P];
        float4 xo = *(const float4*)&xld[cb][3 * 256 + P];
        float hv[4];
        float* cp = (float*)&cs[pass];
        const float* xfp = (const float*)&xf;
        const float* xip = (const float*)&xi;
        const float* xgp = (const float*)&xgv;
        const float* xop = (const float*)&xo;
#pragma unroll
        for (int r = 0; r < 4; ++r) {
          const float fg = sigm(D[0][r] + xfp[r]);
          const float ig = sigm(D[1][r] + xip[r]);
          const float gt = tanh_f(D[2][r] + xgp[r]);
          const float og = sigm(D[3][r] + xop[r]);
          const float cn = cp[r] * fg + ig * gt;
          cp[r] = cn;
          hv[r] = og * tanh_f(cn);
        }
        float4* hpp = &hp[pass];
        (*hpp).x = hv[0]; (*hpp).y = hv[1]; (*hpp).z = hv[2]; (*hpp).w = hv[3];
        v4h h4;
        h4[0] = (_Float16)hv[0]; h4[1] = (_Float16)hv[1];
        h4[2] = (_Float16)hv[2]; h4[3] = (_Float16)hv[3];
        *(v4h*)&hbuf[nb][P] = h4;
      }
    }

    // stage xg(t+1) for the gate lanes of step t+1
    if (t + 1 < SS) *(float2*)&xld[nb][2 * tid] = xpre;

    __syncthreads();   // hbuf[nb], xld[nb] visible; all reads of cb done
  }

  if (act) {
    *(float4*)&hs[(size_t)(SS - 1) * 256 + pb] = hp[0];
    *(float4*)&hs[(size_t)(SS - 1) * 256 + pb + 16] = hp[1];
#pragma unroll
    for (int i = 0; i < 2; ++i) {
      *(float4*)&out[8388608 + (size_t)b * 256 + pb + i * 16] = hp[i];
      *(float4*)&out[8404992 + (size_t)b * 256 + pb + i * 16] = cs[i];
    }
  }
}

// ---------------------------------------------------------------- launch
extern "C" void kernel_launch(void* const* d_in, const int* in_sizes, int n_in,
                              void* d_out, int out_size, void* d_ws, size_t ws_size,
                              hipStream_t stream) {
  const float* x  = (const float*)d_in[0];
  const float* h0 = (const float*)d_in[1];
  const float* c0 = (const float*)d_in[2];
  const float* Wh = (const float*)d_in[3];
  const float* bh = (const float*)d_in[4];
  const float* Wx = (const float*)d_in[5];
  const float* bx = (const float*)d_in[6];
  float* out = (float*)d_out;

  float* xg = (float*)d_ws;   // 32768*1024 floats = 128 MB

  xg_gemm<<<dim3(8192), dim3(256), 0, stream>>>(x, Wx, bx, bh, xg);
  lstm_scan7<<<dim3(64), dim3(512), 0, stream>>>(xg, Wh, h0, c0, out);
}